// Round 8
// baseline (251.831 us; speedup 1.0000x reference)
//
#include <hip/hip_runtime.h>
#include <hip/hip_bf16.h>
#include <cstddef>
#include <cstdint>

#define NN 4096
#define BB 128
#define CH 8

using short8 = __attribute__((ext_vector_type(8))) short;
using f32x4  = __attribute__((ext_vector_type(4))) float;

// visible-prefix limits for folded row r: exclusive = S, inclusive = E
__device__ __forceinline__ void klims(int r, int& S, int& E) {
    if (r == 0) { S = 0; E = 1; return; }
    int j = (31 - __clz(r)) >> 1;
    int g = r >> (2 * j);
    S = g << (2 * j);
    E = (g + 1) << (2 * j);
}

// folded index n -> lattice site (row*64+col)
__device__ __forceinline__ int perm_site(int n) {
    if (n == 0) return 0;
    int j = (31 - __clz(n)) >> 1;
    int g = n >> (2 * j);
    int o = n - (g << (2 * j));
    int side = 1 << j;
    int rr = o >> j, cc = o & (side - 1);
    int i = 5 - j;
    int s = 1 << i, p = 1 << (i + 1);
    int r, c;
    if (g == 1)      { r = s + rr * p; c = s + cc * p; }
    else if (g == 2) { r = s + rr * p; c = cc * p;     }
    else             { r = rr * p;     c = s + cc * p; }
    return r * 64 + c;
}

// lattice site s -> folded index n
__device__ __forceinline__ int inv_site(int s) {
    if (s == 0) return 0;
    int r = s >> 6, c = s & 63;
    int ir = r ? __builtin_ctz(r) : 6;
    int ic = c ? __builtin_ctz(c) : 6;
    int i = ir < ic ? ir : ic;
    int j = 5 - i;
    int rb = (r >> i) & 1, cb = (c >> i) & 1;
    int g = rb ? (cb ? 1 : 2) : 3;
    return (g << (2 * j)) + ((r >> (i + 1)) << j) + (c >> (i + 1));
}

// fragment-order element index for activation storage [k][b] (bf16)
__device__ __forceinline__ size_t fidx(int k, int b) {
    return (size_t)(((k >> 5) * 8 + (b >> 4)) * 512 + ((k >> 2) & 3) * 128 +
                    (b & 15) * 8 + ((k >> 4) & 1) * 4 + (k & 3));
}

__device__ __forceinline__ unsigned short f2bf(float f) {
    __hip_bfloat16 h = __float2bfloat16(f);
    return __builtin_bit_cast(unsigned short, h);
}

// per-tile k-step count (tile-level kmax from its top row)
__device__ __forceinline__ int tile_nt(int M, int tile, int nseg, int excl) {
    int r_top = (M - 1 - tile * 128) & (NN - 1);
    int S, E;
    klims(r_top, S, E);
    int kmax = excl ? S : E;
    return nseg * ((kmax + 63) >> 6);
}

// prepare: pack W0/W1/W2 -> masked bf16 fragment-order Wp, plus fold x -> xf.
// Pack block = (layer, tile, wid 16-row group, seg, chunk of 8 k-steps):
// reads 16 x 2KB contiguous fp32 row pieces, LDS-transposes, stores fragment
// pieces: Wp[slot][wid][half][lane][8 bf16].
__global__ __launch_bounds__(256) void prepare_k(
        const float* __restrict__ x, unsigned short* __restrict__ xf,
        const float* __restrict__ W0, const float* __restrict__ W1,
        const float* __restrict__ W2, unsigned short* __restrict__ Wp,
        int np0, int np01, int nptot, int s1, int s2) {
    int b = (int)blockIdx.x;
    int tid = threadIdx.x;
    if (b >= nptot) {
        // fold part
        int gid = (b - nptot) * 256 + tid;   // b*4096 + s
        int bb = gid >> 12, s = gid & 4095;
        float v = x[gid];
        int n = inv_site(s);
        xf[fidx(n, bb)] = f2bf(v);
        return;
    }
    const float* W;
    int M, nseg, excl, sb;
    if (b < np0)       { W = W0; M = 2 * NN; nseg = 1; excl = 1; sb = 0; }
    else if (b < np01) { b -= np0; W = W1; M = 2 * NN; nseg = 2; excl = 0; sb = s1; }
    else               { b -= np01; W = W2; M = NN; nseg = 2; excl = 0; sb = s2; }
    const int Ktot = nseg * NN;

    int tile = 0, cum = 0, nkt = 0;
    for (;;) {
        int nt = tile_nt(M, tile, nseg, excl);
        nkt = nt / nseg;
        int blocks = nseg * ((nkt + 7) >> 3) * 8;
        if (b < cum + blocks) break;
        cum += blocks;
        sb += nt;
        ++tile;
    }
    int rem = b - cum;
    int c8cnt = (nkt + 7) >> 3;
    int seg = rem / (c8cnt * 8);
    int rem2 = rem - seg * c8cnt * 8;
    int c8 = rem2 >> 3;
    int wid = rem2 & 7;
    int r0 = M - 128 - tile * 128;
    int rw0 = r0 + wid * 16;

    int rowl = tid >> 4;         // 0..15
    int q4   = tid & 15;         // float4 index within 64-k step
    int r    = rw0 + rowl;
    int S, E;
    klims(r & (NN - 1), S, E);
    int kl = excl ? S : E;

    __shared__ unsigned short lds[8192];  // 8 steps x [2 half][64 lane][8]

    const float* wr = W + (size_t)r * Ktot + seg * NN + c8 * 512 + q4 * 4;
    int half  = q4 >> 3;
    int ebase = ((q4 >> 2) & 1) * 4;
    int lane  = (q4 & 3) * 16 + rowl;
    int kloc0 = c8 * 512 + q4 * 4;

#pragma unroll
    for (int j = 0; j < 8; ++j) {
        if (c8 * 8 + j >= nkt) break;
        float4 v = *(const float4*)(wr + j * 64);
        int kb = kloc0 + j * 64;
        ushort4 u;
        u.x = f2bf(kb + 0 < kl ? v.x : 0.0f);
        u.y = f2bf(kb + 1 < kl ? v.y : 0.0f);
        u.z = f2bf(kb + 2 < kl ? v.z : 0.0f);
        u.w = f2bf(kb + 3 < kl ? v.w : 0.0f);
        *(ushort4*)&lds[j * 1024 + half * 512 + lane * 8 + ebase] = u;
    }
    __syncthreads();
    int smax = nkt - c8 * 8;
    if (smax > 8) smax = 8;
#pragma unroll
    for (int v = 0; v < 4; ++v) {
        int gi = v * 256 + tid;
        int j2 = gi >> 7;
        if (j2 >= smax) break;
        int lp = gi & 127;
        size_t slot = (size_t)sb + (size_t)seg * nkt + c8 * 8 + j2;
        *(short8*)&Wp[(slot * 8 + wid) * 1024 + lp * 8] =
            *(const short8*)&lds[j2 * 1024 + lp * 8];
    }
}

// Lean masked GEMM: Wp bf16 fragment-order, A bf16 fragment-order.
// Flattened queue: block = (tile of 128 rows, CH k-steps). 8 waves x 16 rows.
// Per k-step: 2 Wp loads + 16 A loads + 16 MFMA. fp32 partial at blockIdx slot.
template <bool EXCL>
__global__ __launch_bounds__(512, 4) void made_gemm8(
        const unsigned short* __restrict__ A, const unsigned short* __restrict__ Wp,
        float* __restrict__ partial, int M, int nseg) {
    int b = (int)blockIdx.x, tile = 0, cbase = 0, nt = 0;
    size_t sbase = 0;
    for (;;) {
        nt = tile_nt(M, tile, nseg, EXCL ? 1 : 0);
        int cnt = (nt + CH - 1) / CH;
        if (b < cbase + cnt) break;
        cbase += cnt;
        sbase += nt;
        ++tile;
    }
    const int nkt = nt / nseg;
    const int t0 = (b - cbase) * CH;
    const int t1 = (t0 + CH < nt) ? t0 + CH : nt;

    const int wid  = threadIdx.x >> 6;
    const int lane = threadIdx.x & 63;

    f32x4 acc[8] = {};
    const unsigned short* wpb = Wp + ((size_t)sbase * 8 + wid) * 1024 + lane * 8;

    for (int t = t0; t < t1; ++t) {
        const unsigned short* wp_ = wpb + (size_t)t * 8192;
        short8 wf0 = *(const short8*)wp_;
        short8 wf1 = *(const short8*)(wp_ + 512);
        int sg = (nseg == 2 && t >= nkt) ? 1 : 0;
        int kb = (t - sg * nkt) << 6;
        const unsigned short* ab =
            A + (size_t)((sg * NN + kb) >> 5) * 4096 + lane * 8;
#pragma unroll
        for (int q = 0; q < 8; ++q) {
            short8 a0 = *(const short8*)(ab + q * 512);
            short8 a1 = *(const short8*)(ab + 4096 + q * 512);
            acc[q] = __builtin_amdgcn_mfma_f32_16x16x32_bf16(wf0, a0, acc[q], 0, 0, 0);
            acc[q] = __builtin_amdgcn_mfma_f32_16x16x32_bf16(wf1, a1, acc[q], 0, 0, 0);
        }
    }

    const int kq = lane >> 4, row = lane & 15;
    float* pc = partial + (size_t)blockIdx.x * 16384 + (wid * 16 + kq * 4) * 128 + row;
#pragma unroll
    for (int q = 0; q < 8; ++q)
#pragma unroll
        for (int i = 0; i < 4; ++i)
            pc[(size_t)i * 128 + q * 16] = acc[q][i];
}

// reduce partial slots + bias + prelu -> bf16 fragment-order activations
__global__ void reduce01_k(const float* __restrict__ p, const float* __restrict__ bias,
                           const float* __restrict__ alpha, unsigned short* __restrict__ h,
                           int M, int nseg, int excl) {
    int gid = blockIdx.x * 256 + threadIdx.x;   // (M/4)*128 threads
    int m0 = (gid >> 7) << 2;
    int b  = gid & 127;
    int tile_m = (M - 128 - (m0 & ~127)) >> 7;
    int basep = 0, cntm = 0;
    for (int tt = 0; tt <= tile_m; ++tt) {
        int nt = tile_nt(M, tt, nseg, excl);
        int cnt = (nt + CH - 1) / CH;
        if (tt == tile_m) cntm = cnt;
        else basep += cnt;
    }
    const float* ps = p + (size_t)basep * 16384 + (m0 & 127) * 128 + b;
    f32x4 v = {};
    for (int s = 0; s < cntm; ++s) {
        v[0] += ps[0];
        v[1] += ps[128];
        v[2] += ps[256];
        v[3] += ps[384];
        ps += 16384;
    }
    ushort4 st;
    float t;
    t = v[0] + bias[m0 + 0]; t = fmaxf(t, 0.f) + alpha[m0 + 0] * fminf(t, 0.f); st.x = f2bf(t);
    t = v[1] + bias[m0 + 1]; t = fmaxf(t, 0.f) + alpha[m0 + 1] * fminf(t, 0.f); st.y = f2bf(t);
    t = v[2] + bias[m0 + 2]; t = fmaxf(t, 0.f) + alpha[m0 + 2] * fminf(t, 0.f); st.z = f2bf(t);
    t = v[3] + bias[m0 + 3]; t = fmaxf(t, 0.f) + alpha[m0 + 3] * fminf(t, 0.f); st.w = f2bf(t);
    *(ushort4*)&h[fidx(m0, b)] = st;
}

// reduce partial slots + bias + sigmoid + unfold scatter -> out[b][site]
__global__ void reduce2_k(const float* __restrict__ p, const float* __restrict__ b2,
                          float* __restrict__ out) {
    int gid = blockIdx.x * 256 + threadIdx.x;   // NN*BB threads, n-major
    int n = gid >> 7;
    int b = gid & 127;
    int tile_m = (NN - 128 - (n & ~127)) >> 7;
    int basep = 0, cntm = 0;
    for (int tt = 0; tt <= tile_m; ++tt) {
        int nt = tile_nt(NN, tt, 2, 0);
        int cnt = (nt + CH - 1) / CH;
        if (tt == tile_m) cntm = cnt;
        else basep += cnt;
    }
    const float* ps = p + (size_t)basep * 16384 + (n & 127) * 128 + b;
    float v = 0.0f;
    for (int s = 0; s < cntm; ++s) { v += *ps; ps += 16384; }
    v += b2[n];
    float sg = 1.0f / (1.0f + __expf(-v));
    if (n == 0) sg = 0.5f;
    out[(size_t)b * NN + perm_site(n)] = sg;
}

// ---------------- host ----------------
static inline void h_klims(int r, int& S, int& E) {
    if (r == 0) { S = 0; E = 1; return; }
    int j = (31 - __builtin_clz((unsigned)r)) >> 1;
    int g = r >> (2 * j);
    S = g << (2 * j);
    E = (g + 1) << (2 * j);
}

static inline int h_tile_nt(int M, int tile, int nseg, int excl) {
    int r_top = (M - 1 - tile * 128) & (NN - 1);
    int S, E;
    h_klims(r_top, S, E);
    int kmax = excl ? S : E;
    return nseg * ((kmax + 63) >> 6);
}

static inline void layer_counts(int M, int nseg, int excl,
                                int& chunks, int& slots, int& packs) {
    chunks = 0; slots = 0; packs = 0;
    for (int tile = 0; tile < M / 128; ++tile) {
        int nt = h_tile_nt(M, tile, nseg, excl);
        int nkt = nt / nseg;
        chunks += (nt + CH - 1) / CH;
        slots += nt;
        packs += nseg * ((nkt + 7) >> 3) * 8;
    }
}

extern "C" void kernel_launch(void* const* d_in, const int* in_sizes, int n_in,
                              void* d_out, int out_size, void* d_ws, size_t ws_size,
                              hipStream_t stream) {
    const float* x  = (const float*)d_in[0];
    const float* W0 = (const float*)d_in[1];
    const float* b0 = (const float*)d_in[2];
    const float* a1 = (const float*)d_in[3];
    const float* W1 = (const float*)d_in[4];
    const float* b1 = (const float*)d_in[5];
    const float* a2 = (const float*)d_in[6];
    const float* W2 = (const float*)d_in[7];
    const float* b2 = (const float*)d_in[8];

    int c0, s0, p0, c1, s1n, p1, c2, s2n, p2;
    layer_counts(2 * NN, 1, 1, c0, s0, p0);
    layer_counts(2 * NN, 2, 0, c1, s1n, p1);
    layer_counts(NN, 2, 0, c2, s2n, p2);
    int np0 = p0, np01 = p0 + p1, nptot = p0 + p1 + p2;
    int slot1 = s0, slot2 = s0 + s1n, slots_total = s0 + s1n + s2n;
    int cmax = c0 > c1 ? c0 : c1;
    if (c2 > cmax) cmax = c2;

    char* ws = (char*)d_ws;
    unsigned short* xf = (unsigned short*)ws;                 // 1 MB
    unsigned short* h0 = (unsigned short*)(ws + (1 << 20));   // 2 MB
    unsigned short* h1 = (unsigned short*)(ws + (3 << 20));   // 2 MB
    float*          pp = (float*)(ws + (5 << 20));            // partials (chunks x 64KB)
    size_t wp_off = (size_t)(5 << 20) + (size_t)cmax * 65536;
    wp_off = (wp_off + 255) & ~(size_t)255;
    unsigned short* Wp = (unsigned short*)(ws + wp_off);      // slots x 16KB

    // prepare: pack all W layers (masked bf16 fragment order) + fold x
    prepare_k<<<nptot + 2048, 256, 0, stream>>>(
        x, xf, W0, W1, W2, Wp, np0, np01, nptot, slot1, slot2);

    made_gemm8<true><<<c0, 512, 0, stream>>>(xf, Wp, pp, 2 * NN, 1);
    reduce01_k<<<1024, 256, 0, stream>>>(pp, b0, a1, h0, 2 * NN, 1, 1);

    made_gemm8<false><<<c1, 512, 0, stream>>>(h0, Wp + (size_t)slot1 * 8192, pp, 2 * NN, 2);
    reduce01_k<<<1024, 256, 0, stream>>>(pp, b1, a2, h1, 2 * NN, 2, 0);

    made_gemm8<false><<<c2, 512, 0, stream>>>(h1, Wp + (size_t)slot2 * 8192, pp, NN, 2);
    reduce2_k<<<2048, 256, 0, stream>>>(pp, b2, (float*)d_out);
}

// Round 10
// 208.864 us; speedup vs baseline: 1.2057x; 1.2057x over previous
//
#include <hip/hip_runtime.h>
#include <hip/hip_bf16.h>
#include <cstddef>
#include <cstdint>

#define NN 4096
#define BB 128

using short8 = __attribute__((ext_vector_type(8))) short;
using f32x4  = __attribute__((ext_vector_type(4))) float;

// visible-prefix limits for folded row r: exclusive = S, inclusive = E
__device__ __forceinline__ void klims(int r, int& S, int& E) {
    if (r == 0) { S = 0; E = 1; return; }
    int j = (31 - __clz(r)) >> 1;
    int g = r >> (2 * j);
    S = g << (2 * j);
    E = (g + 1) << (2 * j);
}

// folded index n -> lattice site (row*64+col)
__device__ __forceinline__ int perm_site(int n) {
    if (n == 0) return 0;
    int j = (31 - __clz(n)) >> 1;
    int g = n >> (2 * j);
    int o = n - (g << (2 * j));
    int side = 1 << j;
    int rr = o >> j, cc = o & (side - 1);
    int i = 5 - j;
    int s = 1 << i, p = 1 << (i + 1);
    int r, c;
    if (g == 1)      { r = s + rr * p; c = s + cc * p; }
    else if (g == 2) { r = s + rr * p; c = cc * p;     }
    else             { r = rr * p;     c = s + cc * p; }
    return r * 64 + c;
}

// lattice site s -> folded index n
__device__ __forceinline__ int inv_site(int s) {
    if (s == 0) return 0;
    int r = s >> 6, c = s & 63;
    int ir = r ? __builtin_ctz(r) : 6;
    int ic = c ? __builtin_ctz(c) : 6;
    int i = ir < ic ? ir : ic;
    int j = 5 - i;
    int rb = (r >> i) & 1, cb = (c >> i) & 1;
    int g = rb ? (cb ? 1 : 2) : 3;
    return (g << (2 * j)) + ((r >> (i + 1)) << j) + (c >> (i + 1));
}

// fragment-order element index for activation storage [k][b] (bf16)
__device__ __forceinline__ size_t fidx(int k, int b) {
    return (size_t)(((k >> 5) * 8 + (b >> 4)) * 512 + ((k >> 2) & 3) * 128 +
                    (b & 15) * 8 + ((k >> 4) & 1) * 4 + (k & 3));
}

__device__ __forceinline__ unsigned short f2bf(float f) {
    __hip_bfloat16 h = __float2bfloat16(f);
    return __builtin_bit_cast(unsigned short, h);
}

// non-temporal helpers (native ext-vector types — HIP float4 struct is rejected)
__device__ __forceinline__ f32x4 nt_load4(const float* p) {
    return __builtin_nontemporal_load((const f32x4*)p);
}
__device__ __forceinline__ float nt_load1(const float* p) {
    return __builtin_nontemporal_load(p);
}
__device__ __forceinline__ void nt_store1(float* p, float v) {
    __builtin_nontemporal_store(v, p);
}

// per-tile k-step count (tile-level kmax from its top row), uniform helper
__device__ __forceinline__ int tile_nt(int M, int tile, int nseg, int excl) {
    int r_top = (M - 1 - tile * 128) & (NN - 1);
    int S, E;
    klims(r_top, S, E);
    int kmax = excl ? S : E;
    return nseg * ((kmax + 63) >> 6);
}

// fold: xf_frag[n][b] = x[b][site(n)] as bf16, coalesced reads over x
__global__ void fold_k(const float* __restrict__ x, unsigned short* __restrict__ xf) {
    int gid = blockIdx.x * 256 + threadIdx.x;  // b*4096 + s
    int b = gid >> 12, s = gid & 4095;
    float v = x[gid];
    int n = inv_site(s);
    xf[fidx(n, b)] = f2bf(v);
}

// Masked GEMM, flattened work queue: block = (tile of 128 rows, CHUNK k-steps).
// 8 waves x 16 rows; W loads NON-TEMPORAL (protect A in L2); per-wave prefix
// masking at W load; fp32 partial (nt stores) at blockIdx slot.
template <bool EXCL>
__global__ __launch_bounds__(512, 2) void made_gemm9(
        const unsigned short* __restrict__ A, const float* __restrict__ W,
        float* __restrict__ partial, int M, int Ktot, int nseg, int CH) {
    // uniform block -> (tile, chunk) lookup
    int b = (int)blockIdx.x, tile = 0, base = 0, nt = 0;
    for (;;) {
        nt = tile_nt(M, tile, nseg, EXCL ? 1 : 0);
        int cnt = (nt + CH - 1) / CH;
        if (b < base + cnt) break;
        base += cnt;
        ++tile;
    }
    const int nkt = nt / nseg;
    const int t0 = (b - base) * CH;
    const int t1 = (t0 + CH < nt) ? t0 + CH : nt;

    const int tid  = threadIdx.x;
    const int wid  = tid >> 6;
    const int lane = tid & 63;
    const int r0   = M - 128 - tile * 128;
    const int rw0  = r0 + wid * 16;
    const int rch  = rw0 & (NN - 1);
    const int row  = lane & 15;
    const int kq   = lane >> 4;

    int S, E;
    klims(rch + row, S, E);
    const int kl = EXCL ? S : E;        // this lane-row's seg-local prefix limit
    klims(rch, S, E);
    const int wkmin = EXCL ? S : E;     // wave row-0 limit (monotone min)

    f32x4 acc[8] = {};
    const float* wrow = W + (size_t)(rw0 + row) * Ktot + kq * 4;

    f32x4 wbA[4], wbB[4];

#define ISSUE_W(T, WB)                                                        \
    {                                                                         \
        int sg_ = (nseg == 2 && (T) >= nkt) ? 1 : 0;                          \
        const float* wp_ = wrow + sg_ * NN + (((T) - sg_ * nkt) << 6);        \
        WB[0] = nt_load4(wp_);                                                \
        WB[1] = nt_load4(wp_ + 16);                                           \
        WB[2] = nt_load4(wp_ + 32);                                           \
        WB[3] = nt_load4(wp_ + 48);                                           \
    }

#define COMPUTE(T, WB, PRE, WN)                                               \
    {                                                                         \
        int sg_ = (nseg == 2 && (T) >= nkt) ? 1 : 0;                          \
        int kb_ = ((T) - sg_ * nkt) << 6;                                     \
        const unsigned short* ab_ =                                           \
            A + (size_t)((sg_ * NN + kb_) >> 5) * 4096 + lane * 8;            \
        short8 av_[16];                                                       \
        _Pragma("unroll")                                                     \
        for (int q_ = 0; q_ < 8; ++q_) {                                      \
            av_[2 * q_]     = *(const short8*)(ab_ + q_ * 512);               \
            av_[2 * q_ + 1] = *(const short8*)(ab_ + 4096 + q_ * 512);        \
        }                                                                     \
        if (PRE) ISSUE_W((T) + 1, WN);                                        \
        float wv_[16];                                                        \
        _Pragma("unroll")                                                     \
        for (int i_ = 0; i_ < 4; ++i_) {                                      \
            wv_[4 * i_ + 0] = WB[i_][0];                                      \
            wv_[4 * i_ + 1] = WB[i_][1];                                      \
            wv_[4 * i_ + 2] = WB[i_][2];                                      \
            wv_[4 * i_ + 3] = WB[i_][3];                                      \
        }                                                                     \
        if (kb_ + 64 > wkmin) {                                               \
            int k0_ = kb_ + kq * 4;                                           \
            _Pragma("unroll")                                                 \
            for (int i_ = 0; i_ < 4; ++i_) {                                  \
                _Pragma("unroll")                                             \
                for (int j_ = 0; j_ < 4; ++j_)                                \
                    if (k0_ + i_ * 16 + j_ >= kl) wv_[4 * i_ + j_] = 0.0f;    \
            }                                                                 \
        }                                                                     \
        short8 wf0_, wf1_;                                                    \
        _Pragma("unroll")                                                     \
        for (int e_ = 0; e_ < 8; ++e_) {                                      \
            wf0_[e_] = (short)f2bf(wv_[e_]);                                  \
            wf1_[e_] = (short)f2bf(wv_[8 + e_]);                              \
        }                                                                     \
        _Pragma("unroll")                                                     \
        for (int q_ = 0; q_ < 8; ++q_) {                                      \
            acc[q_] = __builtin_amdgcn_mfma_f32_16x16x32_bf16(                \
                wf0_, av_[2 * q_], acc[q_], 0, 0, 0);                         \
            acc[q_] = __builtin_amdgcn_mfma_f32_16x16x32_bf16(                \
                wf1_, av_[2 * q_ + 1], acc[q_], 0, 0, 0);                     \
        }                                                                     \
    }

    {
        int t = t0;
        ISSUE_W(t, wbA);
        while (true) {
            bool pre = (t + 1 < t1);
            COMPUTE(t, wbA, pre, wbB);
            if (!pre) break;
            ++t;
            pre = (t + 1 < t1);
            COMPUTE(t, wbB, pre, wbA);
            if (!pre) break;
            ++t;
        }
    }
#undef ISSUE_W
#undef COMPUTE

    // fp32 partial tile [128 rows][128 b] at this block's slot (nt stores)
    float* pc = partial + (size_t)blockIdx.x * 16384 + (wid * 16 + kq * 4) * 128 + row;
#pragma unroll
    for (int q = 0; q < 8; ++q)
#pragma unroll
        for (int i = 0; i < 4; ++i)
            nt_store1(&pc[(size_t)i * 128 + q * 16], acc[q][i]);
}

// reduce partial slots + bias + prelu -> bf16 fragment-order activations
__global__ void reduce01_k(const float* __restrict__ p, const float* __restrict__ bias,
                           const float* __restrict__ alpha, unsigned short* __restrict__ h,
                           int M, int nseg, int excl, int CH) {
    int gid = blockIdx.x * 256 + threadIdx.x;   // (M/4)*128 threads
    int m0 = (gid >> 7) << 2;
    int b  = gid & 127;
    int tile_m = (M - 128 - (m0 & ~127)) >> 7;
    int basep = 0, cntm = 0;
    for (int tt = 0; tt <= tile_m; ++tt) {
        int nt = tile_nt(M, tt, nseg, excl);
        int cnt = (nt + CH - 1) / CH;
        if (tt == tile_m) cntm = cnt;
        else basep += cnt;
    }
    const float* ps = p + (size_t)basep * 16384 + (m0 & 127) * 128 + b;
    f32x4 v = {};
    for (int s = 0; s < cntm; ++s) {
        v[0] += nt_load1(ps);
        v[1] += nt_load1(ps + 128);
        v[2] += nt_load1(ps + 256);
        v[3] += nt_load1(ps + 384);
        ps += 16384;
    }
    ushort4 st;
    float t;
    t = v[0] + bias[m0 + 0]; t = fmaxf(t, 0.f) + alpha[m0 + 0] * fminf(t, 0.f); st.x = f2bf(t);
    t = v[1] + bias[m0 + 1]; t = fmaxf(t, 0.f) + alpha[m0 + 1] * fminf(t, 0.f); st.y = f2bf(t);
    t = v[2] + bias[m0 + 2]; t = fmaxf(t, 0.f) + alpha[m0 + 2] * fminf(t, 0.f); st.z = f2bf(t);
    t = v[3] + bias[m0 + 3]; t = fmaxf(t, 0.f) + alpha[m0 + 3] * fminf(t, 0.f); st.w = f2bf(t);
    *(ushort4*)&h[fidx(m0, b)] = st;
}

// reduce partial slots + bias + sigmoid + unfold scatter -> out[b][site]
__global__ void reduce2_k(const float* __restrict__ p, const float* __restrict__ b2,
                          float* __restrict__ out, int CH) {
    int gid = blockIdx.x * 256 + threadIdx.x;   // NN*BB threads, n-major
    int n = gid >> 7;
    int b = gid & 127;
    int tile_m = (NN - 128 - (n & ~127)) >> 7;
    int basep = 0, cntm = 0;
    for (int tt = 0; tt <= tile_m; ++tt) {
        int nt = tile_nt(NN, tt, 2, 0);
        int cnt = (nt + CH - 1) / CH;
        if (tt == tile_m) cntm = cnt;
        else basep += cnt;
    }
    const float* ps = p + (size_t)basep * 16384 + (n & 127) * 128 + b;
    float v = 0.0f;
    for (int s = 0; s < cntm; ++s) { v += nt_load1(ps); ps += 16384; }
    v += b2[n];
    float sg = 1.0f / (1.0f + __expf(-v));
    if (n == 0) sg = 0.5f;
    out[(size_t)b * NN + perm_site(n)] = sg;
}

// ---------------- host ----------------
static inline void h_klims(int r, int& S, int& E) {
    if (r == 0) { S = 0; E = 1; return; }
    int j = (31 - __builtin_clz((unsigned)r)) >> 1;
    int g = r >> (2 * j);
    S = g << (2 * j);
    E = (g + 1) << (2 * j);
}

static inline int grid_for(int M, int nseg, int excl, int CH) {
    int nb = 0;
    for (int tile = 0; tile < M / 128; ++tile) {
        int r_top = (M - 1 - tile * 128) & (NN - 1);
        int S, E;
        h_klims(r_top, S, E);
        int kmax = excl ? S : E;
        int nt = nseg * ((kmax + 63) >> 6);
        nb += (nt + CH - 1) / CH;
    }
    return nb;
}

extern "C" void kernel_launch(void* const* d_in, const int* in_sizes, int n_in,
                              void* d_out, int out_size, void* d_ws, size_t ws_size,
                              hipStream_t stream) {
    const float* x  = (const float*)d_in[0];
    const float* W0 = (const float*)d_in[1];
    const float* b0 = (const float*)d_in[2];
    const float* a1 = (const float*)d_in[3];
    const float* W1 = (const float*)d_in[4];
    const float* b1 = (const float*)d_in[5];
    const float* a2 = (const float*)d_in[6];
    const float* W2 = (const float*)d_in[7];
    const float* b2 = (const float*)d_in[8];

    char* ws = (char*)d_ws;
    unsigned short* xf = (unsigned short*)ws;                 // 1 MB
    unsigned short* h0 = (unsigned short*)(ws + (1 << 20));   // 2 MB
    unsigned short* h1 = (unsigned short*)(ws + (3 << 20));   // 2 MB
    float*          pp = (float*)(ws + (5 << 20));            // partials

    // smallest CHUNK whose partial buffer fits the workspace
    int CH = 128;
    int g0 = 0, g1 = 0, g2 = 0;
    const int cands[5] = {8, 16, 32, 64, 128};
    for (int ci = 0; ci < 5; ++ci) {
        int c = cands[ci];
        int a = grid_for(2 * NN, 1, 1, c);
        int bA = grid_for(2 * NN, 2, 0, c);
        int cC = grid_for(NN, 2, 0, c);
        int gmax = a > bA ? a : bA;
        if (cC > gmax) gmax = cC;
        size_t need = (size_t)(5 << 20) + (size_t)gmax * 65536;
        if (need <= ws_size || ci == 4) {
            CH = c; g0 = a; g1 = bA; g2 = cC;
            break;
        }
    }

    fold_k<<<2048, 256, 0, stream>>>(x, xf);

    made_gemm9<true><<<g0, 512, 0, stream>>>(xf, W0, pp, 2 * NN, NN, 1, CH);
    reduce01_k<<<1024, 256, 0, stream>>>(pp, b0, a1, h0, 2 * NN, 1, 1, CH);

    made_gemm9<false><<<g1, 512, 0, stream>>>(h0, W1, pp, 2 * NN, 2 * NN, 2, CH);
    reduce01_k<<<1024, 256, 0, stream>>>(pp, b1, a2, h1, 2 * NN, 2, 0, CH);

    made_gemm9<false><<<g2, 512, 0, stream>>>(h1, W2, pp, NN, 2 * NN, 2, CH);
    reduce2_k<<<2048, 256, 0, stream>>>(pp, b2, (float*)d_out, CH);
}

// Round 11
// 156.675 us; speedup vs baseline: 1.6073x; 1.3331x over previous
//
#include <hip/hip_runtime.h>
#include <hip/hip_bf16.h>
#include <cstddef>
#include <cstdint>

#define NN 4096
#define BB 128

using short8 = __attribute__((ext_vector_type(8))) short;
using f32x4  = __attribute__((ext_vector_type(4))) float;

// visible-prefix limits for folded row r: exclusive = S, inclusive = E
__device__ __forceinline__ void klims(int r, int& S, int& E) {
    if (r == 0) { S = 0; E = 1; return; }
    int j = (31 - __clz(r)) >> 1;
    int g = r >> (2 * j);
    S = g << (2 * j);
    E = (g + 1) << (2 * j);
}

// folded index n -> lattice site (row*64+col)
__device__ __forceinline__ int perm_site(int n) {
    if (n == 0) return 0;
    int j = (31 - __clz(n)) >> 1;
    int g = n >> (2 * j);
    int o = n - (g << (2 * j));
    int side = 1 << j;
    int rr = o >> j, cc = o & (side - 1);
    int i = 5 - j;
    int s = 1 << i, p = 1 << (i + 1);
    int r, c;
    if (g == 1)      { r = s + rr * p; c = s + cc * p; }
    else if (g == 2) { r = s + rr * p; c = cc * p;     }
    else             { r = rr * p;     c = s + cc * p; }
    return r * 64 + c;
}

// lattice site s -> folded index n
__device__ __forceinline__ int inv_site(int s) {
    if (s == 0) return 0;
    int r = s >> 6, c = s & 63;
    int ir = r ? __builtin_ctz(r) : 6;
    int ic = c ? __builtin_ctz(c) : 6;
    int i = ir < ic ? ir : ic;
    int j = 5 - i;
    int rb = (r >> i) & 1, cb = (c >> i) & 1;
    int g = rb ? (cb ? 1 : 2) : 3;
    return (g << (2 * j)) + ((r >> (i + 1)) << j) + (c >> (i + 1));
}

// fragment-order element index for activation storage [k][b] (bf16)
__device__ __forceinline__ size_t fidx(int k, int b) {
    return (size_t)(((k >> 5) * 8 + (b >> 4)) * 512 + ((k >> 2) & 3) * 128 +
                    (b & 15) * 8 + ((k >> 4) & 1) * 4 + (k & 3));
}

__device__ __forceinline__ unsigned short f2bf(float f) {
    __hip_bfloat16 h = __float2bfloat16(f);
    return __builtin_bit_cast(unsigned short, h);
}

__device__ __forceinline__ void gload_lds16(const void* g, void* l) {
    __builtin_amdgcn_global_load_lds(
        (const __attribute__((address_space(1))) unsigned int*)g,
        (__attribute__((address_space(3))) unsigned int*)l, 16, 0, 0);
}

// per-tile k-step count (tile-level kmax from its top row), uniform helper
__device__ __forceinline__ int tile_nt(int M, int tile, int nseg, int excl) {
    int r_top = (M - 1 - tile * 128) & (NN - 1);
    int S, E;
    klims(r_top, S, E);
    int kmax = excl ? S : E;
    return nseg * ((kmax + 63) >> 6);
}

// fold: xf_frag[n][b] = x[b][site(n)] as bf16, coalesced reads over x
__global__ void fold_k(const float* __restrict__ x, unsigned short* __restrict__ xf) {
    int gid = blockIdx.x * 256 + threadIdx.x;  // b*4096 + s
    int b = gid >> 12, s = gid & 4095;
    float v = x[gid];
    int n = inv_site(s);
    xf[fidx(n, b)] = f2bf(v);
}

// Masked GEMM: flattened queue, A staged to LDS (shared by 8 waves, dbuf),
// W streamed to regs (2-deep). Block = (tile 128 rows, CH k-steps), 512 thr.
// Per k-step per wave: 2 global_load_lds + 4 W dwordx4 + 16 ds_read + 16 MFMA.
template <bool EXCL>
__global__ __launch_bounds__(512, 2) void made_gemm11(
        const unsigned short* __restrict__ A, const float* __restrict__ W,
        float* __restrict__ partial, int M, int Ktot, int nseg, int CH) {
    __shared__ __align__(16) char lds[32768];   // 2 x 16KB A k-step buffers

    int b = (int)blockIdx.x, tile = 0, base = 0, nt = 0;
    for (;;) {
        nt = tile_nt(M, tile, nseg, EXCL ? 1 : 0);
        int cnt = (nt + CH - 1) / CH;
        if (b < base + cnt) break;
        base += cnt;
        ++tile;
    }
    const int nkt = nt / nseg;
    const int t0 = (b - base) * CH;
    const int t1 = (t0 + CH < nt) ? t0 + CH : nt;

    const int tid  = threadIdx.x;
    const int wid  = tid >> 6;
    const int lane = tid & 63;
    const int r0   = M - 128 - tile * 128;
    const int rw0  = r0 + wid * 16;
    const int rch  = rw0 & (NN - 1);
    const int row  = lane & 15;
    const int kq   = lane >> 4;

    int S, E;
    klims(rch + row, S, E);
    const int kl = EXCL ? S : E;        // this lane-row's seg-local prefix limit
    klims(rch, S, E);
    const int wkmin = EXCL ? S : E;     // wave row-0 limit (monotone min)

    f32x4 acc[8] = {};
    const float* wrow = W + (size_t)(rw0 + row) * Ktot + kq * 4;
    const char* Ab = (const char*)A;

    float4 wbA[4], wbB[4];

#define ISSUE_W(T, WB)                                                        \
    {                                                                         \
        int sg_ = (nseg == 2 && (T) >= nkt) ? 1 : 0;                          \
        const float* wp_ = wrow + sg_ * NN + (((T) - sg_ * nkt) << 6);        \
        WB[0] = *(const float4*)(wp_);                                        \
        WB[1] = *(const float4*)(wp_ + 16);                                   \
        WB[2] = *(const float4*)(wp_ + 32);                                   \
        WB[3] = *(const float4*)(wp_ + 48);                                   \
    }

#define STAGE_A(T, BUF)                                                       \
    {                                                                         \
        int sg_ = (nseg == 2 && (T) >= nkt) ? 1 : 0;                          \
        int kb_ = ((T) - sg_ * nkt) << 6;                                     \
        const char* src_ = Ab + (size_t)(sg_ * NN + kb_) * 256 +              \
                           wid * 2048 + lane * 16;                            \
        char* dst_ = lds + (BUF) * 16384 + wid * 2048;                        \
        gload_lds16(src_, dst_);                                              \
        gload_lds16(src_ + 1024, dst_ + 1024);                                \
    }

#define COMPUTE_L(T, BUF, WB)                                                 \
    {                                                                         \
        int kb_ = (((T) >= nkt && nseg == 2) ? (T) - nkt : (T)) << 6;         \
        float wv_[16];                                                        \
        _Pragma("unroll")                                                     \
        for (int i_ = 0; i_ < 4; ++i_) {                                      \
            wv_[4 * i_ + 0] = WB[i_].x;                                       \
            wv_[4 * i_ + 1] = WB[i_].y;                                       \
            wv_[4 * i_ + 2] = WB[i_].z;                                       \
            wv_[4 * i_ + 3] = WB[i_].w;                                       \
        }                                                                     \
        if (kb_ + 64 > wkmin) {                                               \
            int k0_ = kb_ + kq * 4;                                           \
            _Pragma("unroll")                                                 \
            for (int i_ = 0; i_ < 4; ++i_) {                                  \
                _Pragma("unroll")                                             \
                for (int j_ = 0; j_ < 4; ++j_)                                \
                    if (k0_ + i_ * 16 + j_ >= kl) wv_[4 * i_ + j_] = 0.0f;    \
            }                                                                 \
        }                                                                     \
        short8 wf0_, wf1_;                                                    \
        _Pragma("unroll")                                                     \
        for (int e_ = 0; e_ < 8; ++e_) {                                      \
            wf0_[e_] = (short)f2bf(wv_[e_]);                                  \
            wf1_[e_] = (short)f2bf(wv_[8 + e_]);                              \
        }                                                                     \
        const char* ab_ = lds + (BUF) * 16384 + lane * 16;                    \
        _Pragma("unroll")                                                     \
        for (int q_ = 0; q_ < 8; ++q_) {                                      \
            short8 a0_ = *(const short8*)(ab_ + q_ * 1024);                   \
            short8 a1_ = *(const short8*)(ab_ + 8192 + q_ * 1024);            \
            acc[q_] = __builtin_amdgcn_mfma_f32_16x16x32_bf16(                \
                wf0_, a0_, acc[q_], 0, 0, 0);                                 \
            acc[q_] = __builtin_amdgcn_mfma_f32_16x16x32_bf16(                \
                wf1_, a1_, acc[q_], 0, 0, 0);                                 \
        }                                                                     \
    }

    {
        int t = t0, buf = 0;
        STAGE_A(t, 0);
        ISSUE_W(t, wbA);
        while (true) {
            __syncthreads();             // drains stage(t)+W(t)
            bool pre = (t + 1 < t1);
            if (pre) { STAGE_A(t + 1, buf ^ 1); ISSUE_W(t + 1, wbB); }
            COMPUTE_L(t, buf, wbA);
            if (!pre) break;
            ++t; buf ^= 1;
            __syncthreads();
            pre = (t + 1 < t1);
            if (pre) { STAGE_A(t + 1, buf ^ 1); ISSUE_W(t + 1, wbA); }
            COMPUTE_L(t, buf, wbB);
            if (!pre) break;
            ++t; buf ^= 1;
        }
    }
#undef ISSUE_W
#undef STAGE_A
#undef COMPUTE_L

    // fp32 partial tile [128 rows][128 b] at this block's slot
    float* pc = partial + (size_t)blockIdx.x * 16384 + (wid * 16 + kq * 4) * 128 + row;
#pragma unroll
    for (int q = 0; q < 8; ++q)
#pragma unroll
        for (int i = 0; i < 4; ++i)
            pc[(size_t)i * 128 + q * 16] = acc[q][i];
}

// reduce partial slots + bias + prelu -> bf16 fragment-order activations
__global__ void reduce01_k(const float* __restrict__ p, const float* __restrict__ bias,
                           const float* __restrict__ alpha, unsigned short* __restrict__ h,
                           int M, int nseg, int excl, int CH) {
    int gid = blockIdx.x * 256 + threadIdx.x;   // (M/4)*128 threads
    int m0 = (gid >> 7) << 2;
    int b  = gid & 127;
    int tile_m = (M - 128 - (m0 & ~127)) >> 7;
    int basep = 0, cntm = 0;
    for (int tt = 0; tt <= tile_m; ++tt) {
        int nt = tile_nt(M, tt, nseg, excl);
        int cnt = (nt + CH - 1) / CH;
        if (tt == tile_m) cntm = cnt;
        else basep += cnt;
    }
    const float* ps = p + (size_t)basep * 16384 + (m0 & 127) * 128 + b;
    f32x4 v = {};
    for (int s = 0; s < cntm; ++s) {
        v[0] += ps[0];
        v[1] += ps[128];
        v[2] += ps[256];
        v[3] += ps[384];
        ps += 16384;
    }
    ushort4 st;
    float t;
    t = v[0] + bias[m0 + 0]; t = fmaxf(t, 0.f) + alpha[m0 + 0] * fminf(t, 0.f); st.x = f2bf(t);
    t = v[1] + bias[m0 + 1]; t = fmaxf(t, 0.f) + alpha[m0 + 1] * fminf(t, 0.f); st.y = f2bf(t);
    t = v[2] + bias[m0 + 2]; t = fmaxf(t, 0.f) + alpha[m0 + 2] * fminf(t, 0.f); st.z = f2bf(t);
    t = v[3] + bias[m0 + 3]; t = fmaxf(t, 0.f) + alpha[m0 + 3] * fminf(t, 0.f); st.w = f2bf(t);
    *(ushort4*)&h[fidx(m0, b)] = st;
}

// reduce partial slots + bias + sigmoid + unfold scatter -> out[b][site]
__global__ void reduce2_k(const float* __restrict__ p, const float* __restrict__ b2,
                          float* __restrict__ out, int CH) {
    int gid = blockIdx.x * 256 + threadIdx.x;   // NN*BB threads, n-major
    int n = gid >> 7;
    int b = gid & 127;
    int tile_m = (NN - 128 - (n & ~127)) >> 7;
    int basep = 0, cntm = 0;
    for (int tt = 0; tt <= tile_m; ++tt) {
        int nt = tile_nt(NN, tt, 2, 0);
        int cnt = (nt + CH - 1) / CH;
        if (tt == tile_m) cntm = cnt;
        else basep += cnt;
    }
    const float* ps = p + (size_t)basep * 16384 + (n & 127) * 128 + b;
    float v = 0.0f;
    for (int s = 0; s < cntm; ++s) { v += *ps; ps += 16384; }
    v += b2[n];
    float sg = 1.0f / (1.0f + __expf(-v));
    if (n == 0) sg = 0.5f;
    out[(size_t)b * NN + perm_site(n)] = sg;
}

// ---------------- host ----------------
static inline void h_klims(int r, int& S, int& E) {
    if (r == 0) { S = 0; E = 1; return; }
    int j = (31 - __builtin_clz((unsigned)r)) >> 1;
    int g = r >> (2 * j);
    S = g << (2 * j);
    E = (g + 1) << (2 * j);
}

static inline int grid_for(int M, int nseg, int excl, int CH) {
    int nb = 0;
    for (int tile = 0; tile < M / 128; ++tile) {
        int r_top = (M - 1 - tile * 128) & (NN - 1);
        int S, E;
        h_klims(r_top, S, E);
        int kmax = excl ? S : E;
        int nt = nseg * ((kmax + 63) >> 6);
        nb += (nt + CH - 1) / CH;
    }
    return nb;
}

extern "C" void kernel_launch(void* const* d_in, const int* in_sizes, int n_in,
                              void* d_out, int out_size, void* d_ws, size_t ws_size,
                              hipStream_t stream) {
    const float* x  = (const float*)d_in[0];
    const float* W0 = (const float*)d_in[1];
    const float* b0 = (const float*)d_in[2];
    const float* a1 = (const float*)d_in[3];
    const float* W1 = (const float*)d_in[4];
    const float* b1 = (const float*)d_in[5];
    const float* a2 = (const float*)d_in[6];
    const float* W2 = (const float*)d_in[7];
    const float* b2 = (const float*)d_in[8];

    char* ws = (char*)d_ws;
    unsigned short* xf = (unsigned short*)ws;                 // 1 MB
    unsigned short* h0 = (unsigned short*)(ws + (1 << 20));   // 2 MB
    unsigned short* h1 = (unsigned short*)(ws + (3 << 20));   // 2 MB
    float*          pp = (float*)(ws + (5 << 20));            // partials

    // smallest CHUNK whose partial buffer fits the workspace
    int CH = 128;
    int g0 = 0, g1 = 0, g2 = 0;
    const int cands[5] = {8, 16, 32, 64, 128};
    for (int ci = 0; ci < 5; ++ci) {
        int c = cands[ci];
        int a = grid_for(2 * NN, 1, 1, c);
        int bA = grid_for(2 * NN, 2, 0, c);
        int cC = grid_for(NN, 2, 0, c);
        int gmax = a > bA ? a : bA;
        if (cC > gmax) gmax = cC;
        size_t need = (size_t)(5 << 20) + (size_t)gmax * 65536;
        if (need <= ws_size || ci == 4) {
            CH = c; g0 = a; g1 = bA; g2 = cC;
            break;
        }
    }

    fold_k<<<2048, 256, 0, stream>>>(x, xf);

    made_gemm11<true><<<g0, 512, 0, stream>>>(xf, W0, pp, 2 * NN, NN, 1, CH);
    reduce01_k<<<1024, 256, 0, stream>>>(pp, b0, a1, h0, 2 * NN, 1, 1, CH);

    made_gemm11<false><<<g1, 512, 0, stream>>>(h0, W1, pp, 2 * NN, 2 * NN, 2, CH);
    reduce01_k<<<1024, 256, 0, stream>>>(pp, b1, a2, h1, 2 * NN, 2, 0, CH);

    made_gemm11<false><<<g2, 512, 0, stream>>>(h1, W2, pp, NN, 2 * NN, 2, CH);
    reduce2_k<<<2048, 256, 0, stream>>>(pp, b2, (float*)d_out, CH);
}